// Round 12
// baseline (895.362 us; speedup 1.0000x reference)
//
#include <hip/hip_runtime.h>
#include <hip/hip_bf16.h>

typedef unsigned short u16;
typedef unsigned int u32;
typedef short bf16x8 __attribute__((ext_vector_type(8)));
typedef float f32x4 __attribute__((ext_vector_type(4)));

#define NTOK 8192
#define HID 768
#define INTER 2048
#define NEXP 8

#define MFMA16(a, b, c) __builtin_amdgcn_mfma_f32_16x16x32_bf16(a, b, c, 0, 0, 0)
#define S_BARRIER() __builtin_amdgcn_s_barrier()
#define WAITVM(n) asm volatile("s_waitcnt vmcnt(" #n ")" ::: "memory")

__device__ __forceinline__ u16 f2bf(float f) {
    u32 u = __builtin_bit_cast(u32, f);
    u32 r = (u + 0x7FFFu + ((u >> 16) & 1u)) >> 16;
    return (u16)r;
}

__device__ __forceinline__ void gld16(const void* g, void* l) {
    __builtin_amdgcn_global_load_lds((const __attribute__((address_space(1))) void*)g,
                                     (__attribute__((address_space(3))) void*)l, 16, 0, 0);
}

// ---------------- router: logits, top-2, softmax; fused x->bf16 and out-zeroing ----------------
__global__ __launch_bounds__(256) void router3(const float* __restrict__ x, const float* __restrict__ rw,
                                               u32* __restrict__ route, float* __restrict__ wslot,
                                               u32* __restrict__ xb32, float4* __restrict__ out4) {
    int wv = threadIdx.x >> 6, ln = threadIdx.x & 63;
    int t = blockIdx.x * 4 + wv;
    if (t >= NTOK) return;
    float4 z = {0.f, 0.f, 0.f, 0.f};
#pragma unroll
    for (int k = 0; k < 3; k++) out4[(size_t)t * 192 + ln + k * 64] = z;
    const float2* x2 = (const float2*)(x + (size_t)t * HID);
    float2 xr2[6];
#pragma unroll
    for (int j = 0; j < 6; j++) xr2[j] = x2[ln + 64 * j];
    u32* xrow = xb32 + (size_t)t * (HID / 2);
#pragma unroll
    for (int j = 0; j < 6; j++)
        xrow[ln + 64 * j] = (u32)f2bf(xr2[j].x) | ((u32)f2bf(xr2[j].y) << 16);
    float lg[NEXP];
#pragma unroll
    for (int e = 0; e < NEXP; e++) {
        const float2* rw2 = (const float2*)(rw + e * HID);
        float a = 0.f;
#pragma unroll
        for (int j = 0; j < 6; j++) {
            float2 r2 = rw2[ln + 64 * j];
            a += xr2[j].x * r2.x + xr2[j].y * r2.y;
        }
#pragma unroll
        for (int off = 32; off; off >>= 1) a += __shfl_xor(a, off);
        lg[e] = a;
    }
    int i0 = 0;
    float v0 = lg[0];
#pragma unroll
    for (int e = 1; e < NEXP; e++)
        if (lg[e] > v0) { v0 = lg[e]; i0 = e; }
    int i1 = -1;
    float v1 = -1e30f;
#pragma unroll
    for (int e = 0; e < NEXP; e++) {
        if (e == i0) continue;
        if (lg[e] > v1) { v1 = lg[e]; i1 = e; }
    }
    float w0 = 1.f / (1.f + __expf(v1 - v0));
    float w1 = 1.f - w0;
    if (ln == 0) {
        wslot[0 * NTOK + t] = w0;
        wslot[1 * NTOK + t] = w1;
        route[t] = (u32)i0 | ((u32)i1 << 8);
    }
}

// ---------------- prep: block 0 = deterministic counting sort + schedule;
//                  blocks 1..N = gu/dn fp32->bf16 convert (overlaps scatter) ----------------
__global__ __launch_bounds__(1024) void prep_kernel(const u32* __restrict__ route, int* __restrict__ counts,
                                                    int* __restrict__ tokslot, int* __restrict__ ntiles,
                                                    int* __restrict__ tiledesc, int* __restrict__ ebase,
                                                    const float* __restrict__ s1, u16* __restrict__ d1, int n1,
                                                    const float* __restrict__ s2, u16* __restrict__ d2, int n2) {
    int tid = threadIdx.x;
    if (blockIdx.x == 0) {
        __shared__ int sc[NEXP][1024];
        u32 rt[8];
        int cnt[NEXP] = {0, 0, 0, 0, 0, 0, 0, 0};
#pragma unroll
        for (int k = 0; k < 8; k++) {
            rt[k] = route[tid * 8 + k];
            cnt[rt[k] & 255]++;
            cnt[(rt[k] >> 8) & 255]++;
        }
#pragma unroll
        for (int e = 0; e < NEXP; e++) sc[e][tid] = cnt[e];
        __syncthreads();
        for (int off = 1; off < 1024; off <<= 1) {
            int v[NEXP];
#pragma unroll
            for (int e = 0; e < NEXP; e++) v[e] = (tid >= off) ? sc[e][tid - off] : 0;
            __syncthreads();
#pragma unroll
            for (int e = 0; e < NEXP; e++)
                if (tid >= off) sc[e][tid] += v[e];
            __syncthreads();
        }
        int ebL[NEXP];
        {
            int b = 0;
#pragma unroll
            for (int e = 0; e < NEXP; e++) { ebL[e] = b; b += sc[e][1023]; }
        }
        int base[NEXP];
#pragma unroll
        for (int e = 0; e < NEXP; e++) base[e] = sc[e][tid] - cnt[e];
#pragma unroll
        for (int k = 0; k < 8; k++) {
            int t = tid * 8 + k;
            int e0 = rt[k] & 255, e1 = (rt[k] >> 8) & 255;
            tokslot[ebL[e0] + base[e0]] = t;
            base[e0]++;
            tokslot[ebL[e1] + base[e1]] = t | (1 << 16);
            base[e1]++;
        }
        if (tid == 0) {
            int tot = 0;
            for (int e = 0; e < NEXP; e++) {
                int c = sc[e][1023];
                counts[e] = c;
                ebase[e] = ebL[e];
                int nt = (c + 255) >> 8;
                for (int q = 0; q < nt; q++) tiledesc[tot++] = (e << 8) | q;
            }
            ntiles[0] = tot;
        }
    } else {
        // convert gu then dn, grid-stride over blocks 1..gridDim-1
        int i = (blockIdx.x - 1) * 1024 + tid;
        int stride = (gridDim.x - 1) * 1024;
        int ntot = n1 + n2;
        for (; i < ntot; i += stride) {
            const float* src;
            u16* dst;
            int k;
            if (i < n1) { src = s1; dst = d1; k = i; }
            else { src = s2; dst = d2; k = i - n1; }
            const float4* s = (const float4*)(src + (size_t)k * 8);
            float4 a = s[0], b = s[1];
            u16 r[8] = {f2bf(a.x), f2bf(a.y), f2bf(a.z), f2bf(a.w),
                        f2bf(b.x), f2bf(b.y), f2bf(b.z), f2bf(b.w)};
            *(uint4*)(dst + (size_t)k * 8) = *(const uint4*)r;
        }
    }
}

// =====================================================================
// gateup: 512 thr (8 waves, 2x4), tile 256 tok x 128 h-cols (256 gu
// rows), BK=32, LDS 2 x 32 KiB dbuf = 64 KiB -> 2 blocks/CU.
// Rationale (R11): supply rate ~ independent resident blocks (8.8/12.5/
// 16.3 B/cyc at 1/2/3 — R6/R8/R9); this tile HALVES total staged bytes
// (A re-read 16x not 32x): 1.33 GB -> 0.79 GB; wall = bytes/rate wins
// even if rate dips to ~12.
// Loop: STAGE(t+1) -> ds_read frags -> 32 MFMA/wave -> vmcnt(0) -> bar.
// Swizzle: 16B-slot ^= (row&3)^((row>>2)&3) on global source (LDS dest
// linear, involution) and on ds_read address.
// =====================================================================

#define GSTG(d, kt)                                          \
    do {                                                     \
        char* base_ = lds + (d)*32768 + (tid << 4);          \
        size_t ko_ = (size_t)(kt)*64;                        \
        gld16(aP[0] + ko_, base_);                           \
        gld16(aP[1] + ko_, base_ + 8192);                    \
        gld16(bP[0] + ko_, base_ + 16384);                   \
        gld16(bP[1] + ko_, base_ + 24576);                   \
    } while (0)

__global__ __launch_bounds__(512, 4) void gateup_mb8(const u16* __restrict__ xb, const u16* __restrict__ gub,
                                                     const int* __restrict__ counts,
                                                     const int* __restrict__ ntiles, const int* __restrict__ tiledesc,
                                                     const int* __restrict__ tokslot, const int* __restrict__ ebase,
                                                     u16* __restrict__ h) {
    if ((int)blockIdx.y >= ntiles[0]) return;
    int td = tiledesc[blockIdx.y];
    int e = td >> 8;
    int cnt = counts[e];
    int eb = ebase[e];
    int row0 = (td & 255) * 256;
    int c0 = blockIdx.x * 128;

    extern __shared__ char lds[];
    int tid = threadIdx.x;
    int wv = tid >> 6, ln = tid & 63;
    int wr = wv >> 2, wc = wv & 3;
    int rsel = ln & 15, g4 = ln >> 4;

    // staging: thread covers rows srow and 128+srow of A and of B; slot tid&3
    int srow = tid >> 2, sl = tid & 3;
    int sswz = ((sl ^ (srow & 3) ^ ((srow >> 2) & 3)) << 4);
    const char* aP[2];
    const char* bP[2];
#pragma unroll
    for (int c = 0; c < 2; c++) {
        int gr = row0 + c * 128 + srow;
        gr = gr < cnt ? gr : cnt - 1;
        int tok = tokslot[eb + gr] & 0xFFFF;
        aP[c] = (const char*)xb + (size_t)tok * (HID * 2) + sswz;
    }
#pragma unroll
    for (int c = 0; c < 2; c++) {
        int r = c * 128 + srow;  // B tile row; group g=r>>6 of 64 (32 gate|32 up)
        int wi = r & 63;
        int b = (wi >> 5) * 2048 + c0 + (r >> 6) * 32 + (wi & 31);
        bP[c] = (const char*)gub + ((size_t)e * 4096 + b) * (HID * 2) + sswz;
    }

    f32x4 acc[8][4];
#pragma unroll
    for (int m_ = 0; m_ < 8; m_++)
#pragma unroll
        for (int n_ = 0; n_ < 4; n_++) acc[m_][n_] = (f32x4)0.f;
    const int sOff = ((g4 ^ (rsel & 3) ^ ((rsel >> 2) & 3)) << 4);
    const int aBase = (wr * 128 + rsel) * 64 + sOff;
    const int bBase = 16384 + (wc * 64 + rsel) * 64 + sOff;
    GSTG(0, 0);
    WAITVM(0);
    S_BARRIER();
    const int NKT = HID / 32;  // 24
    for (int t = 0; t < NKT; ++t) {
        if (t + 1 < NKT) GSTG((t + 1) & 1, t + 1);
        const char* Tb = lds + (t & 1) * 32768;
        bf16x8 af[8], bfr[4];
#pragma unroll
        for (int m_ = 0; m_ < 8; m_++)
            af[m_] = *(const bf16x8*)(Tb + aBase + m_ * 1024);
#pragma unroll
        for (int n_ = 0; n_ < 4; n_++)
            bfr[n_] = *(const bf16x8*)(Tb + bBase + n_ * 1024);
#pragma unroll
        for (int m_ = 0; m_ < 8; m_++)
#pragma unroll
            for (int n_ = 0; n_ < 4; n_++)
                acc[m_][n_] = MFMA16(af[m_], bfr[n_], acc[m_][n_]);
        WAITVM(0);
        S_BARRIER();
    }

    // epilogue: n in {0,1}=gate, n+2=up; h-col = c0 + wc*32 + n*16 + rsel
#pragma unroll
    for (int mg = 0; mg < 8; mg++) {
#pragma unroll
        for (int j = 0; j < 4; j++) {
            int gr = row0 + wr * 128 + mg * 16 + g4 * 4 + j;
            if (gr >= cnt) continue;
            u16* hrow = h + (size_t)(eb + gr) * INTER;
#pragma unroll
            for (int n = 0; n < 2; n++) {
                float gv = acc[mg][n][j];
                float uv = fminf(acc[mg][n + 2][j], 7.0f);
                float sg = gv / (1.0f + __expf(-gv));
                hrow[c0 + wc * 32 + n * 16 + rsel] = f2bf(sg * uv);
            }
        }
    }
}

// =====================================================================
// down (R9-proven geometry): 256 thr (4 waves, 2x2), tile 256 x 128,
// BK=32, LDS 48 KiB dbuf, 3 blocks/CU target, atomic 2-partial epilogue.
// =====================================================================

#define DSTG(d, kt)                                          \
    do {                                                     \
        char* base_ = lds + (d)*24576 + (tid << 4);          \
        size_t ko_ = (size_t)(kt)*64;                        \
        gld16(aP[0] + ko_, base_);                           \
        gld16(aP[1] + ko_, base_ + 4096);                    \
        gld16(aP[2] + ko_, base_ + 8192);                    \
        gld16(aP[3] + ko_, base_ + 12288);                   \
        gld16(bP[0] + ko_, base_ + 16384);                   \
        gld16(bP[1] + ko_, base_ + 20480);                   \
    } while (0)

__global__ __launch_bounds__(256, 3) void down_mb(const u16* __restrict__ hb, const u16* __restrict__ dnb,
                                                  const int* __restrict__ counts,
                                                  const int* __restrict__ ntiles, const int* __restrict__ tiledesc,
                                                  const int* __restrict__ tokslot, const int* __restrict__ ebase,
                                                  const float* __restrict__ wslot, float* __restrict__ out) {
    if ((int)blockIdx.y >= ntiles[0]) return;
    int td = tiledesc[blockIdx.y];
    int e = td >> 8;
    int cnt = counts[e];
    int eb = ebase[e];
    int row0 = (td & 255) * 256;
    int col0 = blockIdx.x * 128;

    extern __shared__ char lds[];
    int tid = threadIdx.x;
    int wv = tid >> 6, ln = tid & 63;
    int wr = wv >> 1, wc = wv & 1;
    int rsel = ln & 15, g4 = ln >> 4;

    int srow = tid >> 2, sl = tid & 3;
    int sswz = ((sl ^ (srow & 3) ^ ((srow >> 2) & 3)) << 4);
    const char* aP[4];
    const char* bP[2];
#pragma unroll
    for (int c = 0; c < 4; c++) {
        int gr = row0 + c * 64 + srow;
        gr = gr < cnt ? gr : cnt - 1;
        aP[c] = (const char*)hb + (size_t)(eb + gr) * (INTER * 2) + sswz;  // contiguous positions
    }
#pragma unroll
    for (int c = 0; c < 2; c++) {
        int r = c * 64 + srow;
        bP[c] = (const char*)dnb + ((size_t)e * HID + col0 + r) * (INTER * 2) + sswz;
    }

    f32x4 acc[8][4];
#pragma unroll
    for (int m_ = 0; m_ < 8; m_++)
#pragma unroll
        for (int n_ = 0; n_ < 4; n_++) acc[m_][n_] = (f32x4)0.f;
    const int sOff = ((g4 ^ (rsel & 3) ^ ((rsel >> 2) & 3)) << 4);
    const int aBase = (wr * 128 + rsel) * 64 + sOff;
    const int bBase = 16384 + (wc * 64 + rsel) * 64 + sOff;
    DSTG(0, 0);
    WAITVM(0);
    S_BARRIER();
    const int NKT = INTER / 32;  // 64
    for (int t = 0; t < NKT; ++t) {
        if (t + 1 < NKT) DSTG((t + 1) & 1, t + 1);
        const char* Tb = lds + (t & 1) * 24576;
        bf16x8 af[8], bfr[4];
#pragma unroll
        for (int m_ = 0; m_ < 8; m_++)
            af[m_] = *(const bf16x8*)(Tb + aBase + m_ * 1024);
#pragma unroll
        for (int n_ = 0; n_ < 4; n_++)
            bfr[n_] = *(const bf16x8*)(Tb + bBase + n_ * 1024);
#pragma unroll
        for (int m_ = 0; m_ < 8; m_++)
#pragma unroll
            for (int n_ = 0; n_ < 4; n_++)
                acc[m_][n_] = MFMA16(af[m_], bfr[n_], acc[m_][n_]);
        WAITVM(0);
        S_BARRIER();
    }

#pragma unroll
    for (int mg = 0; mg < 8; mg++) {
#pragma unroll
        for (int j = 0; j < 4; j++) {
            int gr = row0 + wr * 128 + mg * 16 + g4 * 4 + j;
            if (gr >= cnt) continue;
            int ts = tokslot[eb + gr];
            int tok = ts & 0xFFFF, slot = ts >> 16;
            float w = wslot[slot * NTOK + tok];
#pragma unroll
            for (int n = 0; n < 4; n++) {
                int col = col0 + wc * 64 + n * 16 + rsel;
                atomicAdd(&out[(size_t)tok * HID + col], w * acc[mg][n][j]);
            }
        }
    }
}

// ---------------- launch ----------------
extern "C" void kernel_launch(void* const* d_in, const int* in_sizes, int n_in,
                              void* d_out, int out_size, void* d_ws, size_t ws_size,
                              hipStream_t stream) {
    const float* x = (const float*)d_in[0];
    const float* rw = (const float*)d_in[1];
    const float* gu = (const float*)d_in[2];
    const float* dn = (const float*)d_in[3];
    float* out = (float*)d_out;
    char* ws = (char*)d_ws;

    // workspace layout (bytes)
    int* counts = (int*)(ws + 0);            // 32
    int* ntiles = (int*)(ws + 64);           // 4
    int* ebase = (int*)(ws + 128);           // 32
    int* tiledesc = (int*)(ws + 256);        // 72*4 -> ends 544
    int* tokslot = (int*)(ws + 4096);        // 16384*4 -> ends 69632 (compact: ebase[e]+pos)
    float* wslot = (float*)(ws + 69632);     // 65536 -> ends 135168
    u16* xb = (u16*)(ws + 135168);           // 12,582,912 -> ends 12,718,080
    u16* gub = (u16*)(ws + 12718080);        // 50,331,648 -> ends 63,049,728
    u16* dnb = (u16*)(ws + 63049728);        // 25,165,824 -> ends 88,215,552
    u16* hb = (u16*)(ws + 88215552);         // 67,108,864 -> ends 155,324,416
    // route aliases the head of hb: written by router3, consumed by prep,
    // then hb is (re)written by gateup_mb8 strictly afterwards on the stream.
    u32* route = (u32*)(ws + 88215552);      // 8192*4

    router3<<<NTOK / 4, 256, 0, stream>>>(x, rw, route, wslot, (u32*)xb, (float4*)out);
    prep_kernel<<<2048, 1024, 0, stream>>>(route, counts, tokslot, ntiles, tiledesc, ebase,
                                           gu, gub, NEXP * 2 * INTER * HID / 8,
                                           dn, dnb, NEXP * HID * INTER / 8);
    gateup_mb8<<<dim3(16, 72), 512, 65536, stream>>>(xb, gub, counts, ntiles, tiledesc, tokslot, ebase, hb);
    down_mb<<<dim3(6, 72), 256, 49152, stream>>>(hb, dnb, counts, ntiles, tiledesc, tokslot, ebase, wslot, out);
}

// Round 13
// 302.003 us; speedup vs baseline: 2.9647x; 2.9647x over previous
//
#include <hip/hip_runtime.h>
#include <hip/hip_bf16.h>

typedef unsigned short u16;
typedef unsigned int u32;
typedef short bf16x8 __attribute__((ext_vector_type(8)));
typedef float f32x4 __attribute__((ext_vector_type(4)));

#define NTOK 8192
#define HID 768
#define INTER 2048
#define NEXP 8

#define MFMA16(a, b, c) __builtin_amdgcn_mfma_f32_16x16x32_bf16(a, b, c, 0, 0, 0)
#define S_BARRIER() __builtin_amdgcn_s_barrier()
#define WAITVM(n) asm volatile("s_waitcnt vmcnt(" #n ")" ::: "memory")

__device__ __forceinline__ u16 f2bf(float f) {
    u32 u = __builtin_bit_cast(u32, f);
    u32 r = (u + 0x7FFFu + ((u >> 16) & 1u)) >> 16;
    return (u16)r;
}

__device__ __forceinline__ void gld16(const void* g, void* l) {
    __builtin_amdgcn_global_load_lds((const __attribute__((address_space(1))) void*)g,
                                     (__attribute__((address_space(3))) void*)l, 16, 0, 0);
}

// ---------------- router: logits, top-2, softmax; fused x->bf16 and out-zeroing ----------------
__global__ __launch_bounds__(256) void router3(const float* __restrict__ x, const float* __restrict__ rw,
                                               u32* __restrict__ route, float* __restrict__ wslot,
                                               u32* __restrict__ xb32, float4* __restrict__ out4) {
    int wv = threadIdx.x >> 6, ln = threadIdx.x & 63;
    int t = blockIdx.x * 4 + wv;
    if (t >= NTOK) return;
    float4 z = {0.f, 0.f, 0.f, 0.f};
#pragma unroll
    for (int k = 0; k < 3; k++) out4[(size_t)t * 192 + ln + k * 64] = z;
    const float2* x2 = (const float2*)(x + (size_t)t * HID);
    float2 xr2[6];
#pragma unroll
    for (int j = 0; j < 6; j++) xr2[j] = x2[ln + 64 * j];
    u32* xrow = xb32 + (size_t)t * (HID / 2);
#pragma unroll
    for (int j = 0; j < 6; j++)
        xrow[ln + 64 * j] = (u32)f2bf(xr2[j].x) | ((u32)f2bf(xr2[j].y) << 16);
    float lg[NEXP];
#pragma unroll
    for (int e = 0; e < NEXP; e++) {
        const float2* rw2 = (const float2*)(rw + e * HID);
        float a = 0.f;
#pragma unroll
        for (int j = 0; j < 6; j++) {
            float2 r2 = rw2[ln + 64 * j];
            a += xr2[j].x * r2.x + xr2[j].y * r2.y;
        }
#pragma unroll
        for (int off = 32; off; off >>= 1) a += __shfl_xor(a, off);
        lg[e] = a;
    }
    int i0 = 0;
    float v0 = lg[0];
#pragma unroll
    for (int e = 1; e < NEXP; e++)
        if (lg[e] > v0) { v0 = lg[e]; i0 = e; }
    int i1 = -1;
    float v1 = -1e30f;
#pragma unroll
    for (int e = 0; e < NEXP; e++) {
        if (e == i0) continue;
        if (lg[e] > v1) { v1 = lg[e]; i1 = e; }
    }
    float w0 = 1.f / (1.f + __expf(v1 - v0));
    float w1 = 1.f - w0;
    if (ln == 0) {
        wslot[0 * NTOK + t] = w0;
        wslot[1 * NTOK + t] = w1;
        route[t] = (u32)i0 | ((u32)i1 << 8);
    }
}

// ---------------- prep: block 0 = deterministic counting sort + schedule;
//                  blocks 1..N = gu/dn fp32->bf16 convert (overlaps the sort) ----------------
__global__ __launch_bounds__(1024) void prep_kernel(const u32* __restrict__ route, int* __restrict__ counts,
                                                    int* __restrict__ tokslot, int* __restrict__ ntiles,
                                                    int* __restrict__ tiledesc, int* __restrict__ ebase,
                                                    const float* __restrict__ s1, u16* __restrict__ d1, int n1,
                                                    const float* __restrict__ s2, u16* __restrict__ d2, int n2) {
    int tid = threadIdx.x;
    if (blockIdx.x == 0) {
        __shared__ int sc[NEXP][1024];
        u32 rt[8];
        int cnt[NEXP] = {0, 0, 0, 0, 0, 0, 0, 0};
#pragma unroll
        for (int k = 0; k < 8; k++) {
            rt[k] = route[tid * 8 + k];
            cnt[rt[k] & 255]++;
            cnt[(rt[k] >> 8) & 255]++;
        }
#pragma unroll
        for (int e = 0; e < NEXP; e++) sc[e][tid] = cnt[e];
        __syncthreads();
        for (int off = 1; off < 1024; off <<= 1) {
            int v[NEXP];
#pragma unroll
            for (int e = 0; e < NEXP; e++) v[e] = (tid >= off) ? sc[e][tid - off] : 0;
            __syncthreads();
#pragma unroll
            for (int e = 0; e < NEXP; e++)
                if (tid >= off) sc[e][tid] += v[e];
            __syncthreads();
        }
        int ebL[NEXP];
        {
            int b = 0;
#pragma unroll
            for (int e = 0; e < NEXP; e++) { ebL[e] = b; b += sc[e][1023]; }
        }
        int base[NEXP];
#pragma unroll
        for (int e = 0; e < NEXP; e++) base[e] = sc[e][tid] - cnt[e];
#pragma unroll
        for (int k = 0; k < 8; k++) {
            int t = tid * 8 + k;
            int e0 = rt[k] & 255, e1 = (rt[k] >> 8) & 255;
            tokslot[ebL[e0] + base[e0]] = t;
            base[e0]++;
            tokslot[ebL[e1] + base[e1]] = t | (1 << 16);
            base[e1]++;
        }
        if (tid == 0) {
            int tot = 0;
            for (int e = 0; e < NEXP; e++) {
                int c = sc[e][1023];
                counts[e] = c;
                ebase[e] = ebL[e];
                int nt = (c + 255) >> 8;
                for (int q = 0; q < nt; q++) tiledesc[tot++] = (e << 8) | q;
            }
            ntiles[0] = tot;
        }
    } else {
        int i = (blockIdx.x - 1) * 1024 + tid;
        int stride = (gridDim.x - 1) * 1024;
        int ntot = n1 + n2;
        for (; i < ntot; i += stride) {
            const float* src;
            u16* dst;
            int k;
            if (i < n1) { src = s1; dst = d1; k = i; }
            else { src = s2; dst = d2; k = i - n1; }
            const float4* s = (const float4*)(src + (size_t)k * 8);
            float4 a = s[0], b = s[1];
            u16 r[8] = {f2bf(a.x), f2bf(a.y), f2bf(a.z), f2bf(a.w),
                        f2bf(b.x), f2bf(b.y), f2bf(b.z), f2bf(b.w)};
            *(uint4*)(dst + (size_t)k * 8) = *(const uint4*)r;
        }
    }
}

// =====================================================================
// R9-PROVEN gateup: 256 thr (4 waves, 2x2), tile 256 tok x 64 h-cols
// (128 gu rows), BK=32, LDS 48 KiB dbuf, __launch_bounds__(256,3) ->
// 3 blocks/CU. Measured 133 us (x3 rounds), MfmaUtil ~37%. Geometry is
// at the VGPR-box optimum: wider tiles need acc>128/wave -> spill (R12)
// or 1 block/CU (R6); supply rate scales with resident blocks (R6/R8/R9
// ladder: 8.8/12.5/16.3 B/cyc/CU) and is the binding constraint.
// Loop: STAGE(t+1) -> ds_read frags -> 32 MFMA/wave -> vmcnt(0) -> bar.
// Swizzle: 16B-slot ^= (row&3)^((row>>2)&3) on global source (LDS dest
// linear, involution) and on ds_read address.
// =====================================================================

#define STG(d, kt)                                           \
    do {                                                     \
        char* base_ = lds + (d)*24576 + (tid << 4);          \
        size_t ko_ = (size_t)(kt)*64;                        \
        gld16(aP[0] + ko_, base_);                           \
        gld16(aP[1] + ko_, base_ + 4096);                    \
        gld16(aP[2] + ko_, base_ + 8192);                    \
        gld16(aP[3] + ko_, base_ + 12288);                   \
        gld16(bP[0] + ko_, base_ + 16384);                   \
        gld16(bP[1] + ko_, base_ + 20480);                   \
    } while (0)

#define PIPE_MB(NKT)                                                      \
    f32x4 acc[8][4];                                                      \
    _Pragma("unroll") for (int m_ = 0; m_ < 8; m_++)                      \
        _Pragma("unroll") for (int n_ = 0; n_ < 4; n_++) acc[m_][n_] = (f32x4)0.f; \
    const int sOff = ((g4 ^ (rsel & 3) ^ ((rsel >> 2) & 3)) << 4);        \
    const int aBase = (wr * 128 + rsel) * 64 + sOff;                      \
    const int bBase = 16384 + (wc * 64 + rsel) * 64 + sOff;               \
    STG(0, 0);                                                            \
    WAITVM(0);                                                            \
    S_BARRIER();                                                          \
    for (int t = 0; t < (NKT); ++t) {                                     \
        if (t + 1 < (NKT)) STG((t + 1) & 1, t + 1);                       \
        const char* Tb = lds + (t & 1) * 24576;                           \
        bf16x8 af[8], bfr[4];                                             \
        _Pragma("unroll") for (int m_ = 0; m_ < 8; m_++)                  \
            af[m_] = *(const bf16x8*)(Tb + aBase + m_ * 1024);            \
        _Pragma("unroll") for (int n_ = 0; n_ < 4; n_++)                  \
            bfr[n_] = *(const bf16x8*)(Tb + bBase + n_ * 1024);           \
        _Pragma("unroll") for (int m_ = 0; m_ < 8; m_++)                  \
            _Pragma("unroll") for (int n_ = 0; n_ < 4; n_++)              \
                acc[m_][n_] = MFMA16(af[m_], bfr[n_], acc[m_][n_]);       \
        WAITVM(0);                                                        \
        S_BARRIER();                                                      \
    }

__global__ __launch_bounds__(256, 3) void gateup_mb(const u16* __restrict__ xb, const u16* __restrict__ gub,
                                                    const int* __restrict__ counts,
                                                    const int* __restrict__ ntiles, const int* __restrict__ tiledesc,
                                                    const int* __restrict__ tokslot, const int* __restrict__ ebase,
                                                    u16* __restrict__ h) {
    if ((int)blockIdx.y >= ntiles[0]) return;
    int td = tiledesc[blockIdx.y];
    int e = td >> 8;
    int cnt = counts[e];
    int eb = ebase[e];
    int row0 = (td & 255) * 256;
    int c0 = blockIdx.x * 64;

    extern __shared__ char lds[];
    int tid = threadIdx.x;
    int wv = tid >> 6, ln = tid & 63;
    int wr = wv >> 1, wc = wv & 1;
    int rsel = ln & 15, g4 = ln >> 4;

    int srow = tid >> 2, sl = tid & 3;
    int sswz = ((sl ^ (srow & 3) ^ ((srow >> 2) & 3)) << 4);
    const char* aP[4];
    const char* bP[2];
#pragma unroll
    for (int c = 0; c < 4; c++) {
        int gr = row0 + c * 64 + srow;
        gr = gr < cnt ? gr : cnt - 1;
        int tok = tokslot[eb + gr] & 0xFFFF;
        aP[c] = (const char*)xb + (size_t)tok * (HID * 2) + sswz;
    }
#pragma unroll
    for (int c = 0; c < 2; c++) {
        int r = c * 64 + srow;
        int wi = r & 63;
        int b = (wi >> 5) * 2048 + c0 + (r >> 6) * 32 + (wi & 31);
        bP[c] = (const char*)gub + ((size_t)e * 4096 + b) * (HID * 2) + sswz;
    }

    PIPE_MB(HID / 32)  // 24 K-tiles

    // epilogue: n in {0,1}=gate, n+2=up; h-col = c0 + wc*32 + n*16 + rsel
#pragma unroll
    for (int mg = 0; mg < 8; mg++) {
#pragma unroll
        for (int j = 0; j < 4; j++) {
            int gr = row0 + wr * 128 + mg * 16 + g4 * 4 + j;
            if (gr >= cnt) continue;
            u16* hrow = h + (size_t)(eb + gr) * INTER;
#pragma unroll
            for (int n = 0; n < 2; n++) {
                float gv = acc[mg][n][j];
                float uv = fminf(acc[mg][n + 2][j], 7.0f);
                float sg = gv / (1.0f + __expf(-gv));
                hrow[c0 + wc * 32 + n * 16 + rsel] = f2bf(sg * uv);
            }
        }
    }
}

// =====================================================================
// R9-proven down: 256 thr (4 waves, 2x2), tile 256 x 128, BK=32,
// LDS 48 KiB dbuf, 3 blocks/CU target, atomic 2-partial epilogue
// (R10 proved split-K/4-partial atomics regress; 192-tiles regress R11).
// =====================================================================

__global__ __launch_bounds__(256, 3) void down_mb(const u16* __restrict__ hb, const u16* __restrict__ dnb,
                                                  const int* __restrict__ counts,
                                                  const int* __restrict__ ntiles, const int* __restrict__ tiledesc,
                                                  const int* __restrict__ tokslot, const int* __restrict__ ebase,
                                                  const float* __restrict__ wslot, float* __restrict__ out) {
    if ((int)blockIdx.y >= ntiles[0]) return;
    int td = tiledesc[blockIdx.y];
    int e = td >> 8;
    int cnt = counts[e];
    int eb = ebase[e];
    int row0 = (td & 255) * 256;
    int col0 = blockIdx.x * 128;

    extern __shared__ char lds[];
    int tid = threadIdx.x;
    int wv = tid >> 6, ln = tid & 63;
    int wr = wv >> 1, wc = wv & 1;
    int rsel = ln & 15, g4 = ln >> 4;

    int srow = tid >> 2, sl = tid & 3;
    int sswz = ((sl ^ (srow & 3) ^ ((srow >> 2) & 3)) << 4);
    const char* aP[4];
    const char* bP[2];
#pragma unroll
    for (int c = 0; c < 4; c++) {
        int gr = row0 + c * 64 + srow;
        gr = gr < cnt ? gr : cnt - 1;
        aP[c] = (const char*)hb + (size_t)(eb + gr) * (INTER * 2) + sswz;  // contiguous positions
    }
#pragma unroll
    for (int c = 0; c < 2; c++) {
        int r = c * 64 + srow;
        bP[c] = (const char*)dnb + ((size_t)e * HID + col0 + r) * (INTER * 2) + sswz;
    }

    PIPE_MB(INTER / 32)  // 64 K-tiles

#pragma unroll
    for (int mg = 0; mg < 8; mg++) {
#pragma unroll
        for (int j = 0; j < 4; j++) {
            int gr = row0 + wr * 128 + mg * 16 + g4 * 4 + j;
            if (gr >= cnt) continue;
            int ts = tokslot[eb + gr];
            int tok = ts & 0xFFFF, slot = ts >> 16;
            float w = wslot[slot * NTOK + tok];
#pragma unroll
            for (int n = 0; n < 4; n++) {
                int col = col0 + wc * 64 + n * 16 + rsel;
                atomicAdd(&out[(size_t)tok * HID + col], w * acc[mg][n][j]);
            }
        }
    }
}

// ---------------- launch ----------------
extern "C" void kernel_launch(void* const* d_in, const int* in_sizes, int n_in,
                              void* d_out, int out_size, void* d_ws, size_t ws_size,
                              hipStream_t stream) {
    const float* x = (const float*)d_in[0];
    const float* rw = (const float*)d_in[1];
    const float* gu = (const float*)d_in[2];
    const float* dn = (const float*)d_in[3];
    float* out = (float*)d_out;
    char* ws = (char*)d_ws;

    // workspace layout (bytes)
    int* counts = (int*)(ws + 0);            // 32
    int* ntiles = (int*)(ws + 64);           // 4
    int* ebase = (int*)(ws + 128);           // 32
    int* tiledesc = (int*)(ws + 256);        // 72*4 -> ends 544
    int* tokslot = (int*)(ws + 4096);        // 16384*4 -> ends 69632 (compact: ebase[e]+pos)
    float* wslot = (float*)(ws + 69632);     // 65536 -> ends 135168
    u16* xb = (u16*)(ws + 135168);           // 12,582,912 -> ends 12,718,080
    u16* gub = (u16*)(ws + 12718080);        // 50,331,648 -> ends 63,049,728
    u16* dnb = (u16*)(ws + 63049728);        // 25,165,824 -> ends 88,215,552
    u16* hb = (u16*)(ws + 88215552);         // 67,108,864 -> ends 155,324,416
    // route aliases the head of hb: written by router3, consumed by prep,
    // then hb is (re)written by gateup_mb strictly afterwards on the stream.
    u32* route = (u32*)(ws + 88215552);      // 8192*4

    router3<<<NTOK / 4, 256, 0, stream>>>(x, rw, route, wslot, (u32*)xb, (float4*)out);
    prep_kernel<<<2048, 1024, 0, stream>>>(route, counts, tokslot, ntiles, tiledesc, ebase,
                                           gu, gub, NEXP * 2 * INTER * HID / 8,
                                           dn, dnb, NEXP * HID * INTER / 8);
    gateup_mb<<<dim3(32, 72), 256, 49152, stream>>>(xb, gub, counts, ntiles, tiledesc, tokslot, ebase, hb);
    down_mb<<<dim3(6, 72), 256, 49152, stream>>>(hb, dnb, counts, ntiles, tiledesc, tokslot, ebase, wslot, out);
}